// Round 2
// baseline (1715.498 us; speedup 1.0000x reference)
//
#include <hip/hip_runtime.h>
#include <cstdint>
#include <cstddef>

// Problem constants
#define NN 128   // seq len
#define BB 8     // batch
#define EE 256   // embed
#define HH 256   // hidden
#define SS 256   // segment dim
#define TT 32    // segment threshold
#define G3 768   // 3*H = 3*S
#define HBSTR 264           // LDS bf16 h row stride (pad 256->264, 16B-aligned)
#define HIDOFF 33816576ull  // 8256*8*512, start of `hidden` in d_out (elements)
#define OUT_ELEMS 33820672ull

typedef __attribute__((ext_vector_type(8))) short bf16x8;
typedef __attribute__((ext_vector_type(4))) float f32x4;

__device__ __forceinline__ float bf2f(unsigned short u) {
    union { unsigned u; float f; } v; v.u = ((unsigned)u) << 16; return v.f;
}
__device__ __forceinline__ float bflo(unsigned u) {
    union { unsigned u; float f; } v; v.u = u << 16; return v.f;
}
__device__ __forceinline__ float bfhi(unsigned u) {
    union { unsigned u; float f; } v; v.u = u & 0xffff0000u; return v.f;
}
__device__ __forceinline__ unsigned short f2bf(float f) {
    union { float f; unsigned u; } v; v.f = f;
    unsigned r = v.u + 0x7fffu + ((v.u >> 16) & 1u);   // RNE
    return (unsigned short)(r >> 16);
}
__device__ __forceinline__ float sigm(float x) { return 1.f / (1.f + __expf(-x)); }

// Detect whether float-typed inputs are physically fp32 (vs bf16).
// Genuine bf16 N(0,1/16) halves never have exponent >= 0xC8 (|x|>=2^73);
// random fp32 low-mantissa halves hit that ~22% of the time each.
__device__ __forceinline__ int detect_f32(const void* emb) {
    const unsigned* w = (const unsigned*)emb;
    int bad = 0;
    for (int i = 0; i < 128; ++i) {
        unsigned u = w[i];
        bad |= (((u >> 7)  & 0xFFu) >= 0xC8u);
        bad |= (((u >> 23) & 0xFFu) >= 0xC8u);
    }
    return bad;
}

__device__ __forceinline__ float lds1(const void* p, size_t i, int f32) {
    return f32 ? ((const float*)p)[i] : bf2f(((const unsigned short*)p)[i]);
}
__device__ __forceinline__ bf16x8 load8(const void* p, size_t off, int f32) {
    bf16x8 r;
    if (f32) {
        const float* q = (const float*)p + off;
        float4 a = *(const float4*)q, b = *(const float4*)(q + 4);
        r[0] = (short)f2bf(a.x); r[1] = (short)f2bf(a.y);
        r[2] = (short)f2bf(a.z); r[3] = (short)f2bf(a.w);
        r[4] = (short)f2bf(b.x); r[5] = (short)f2bf(b.y);
        r[6] = (short)f2bf(b.z); r[7] = (short)f2bf(b.w);
    } else {
        r = *(const bf16x8*)((const unsigned short*)p + off);
    }
    return r;
}
__device__ __forceinline__ void outw(void* p, size_t i, float v, int f32) {
    if (f32) ((float*)p)[i] = v;
    else ((unsigned short*)p)[i] = f2bf(v);
}

// ---------------------------------------------------------------------------
// Gate GEMM with fused embedding gather: C[(n,b)][c] = emb[tok[n,b]] . W[c] + bias[c]
__global__ __launch_bounds__(256) void gemm_tok(const int* __restrict__ tok,
                                                const void* __restrict__ emb,
                                                const void* __restrict__ W,
                                                const void* __restrict__ bias,
                                                float* __restrict__ C) {
    const int f32 = detect_f32(emb);
    int idx = blockIdx.x * 256 + threadIdx.x;   // grid = 1024*768 outputs
    int r = idx / G3, c = idx % G3;
    size_t arow = (size_t)tok[r] * EE;
    float acc = 0.f;
    if (f32) {
        const float* a = (const float*)emb + arow;
        const float* w = (const float*)W + (size_t)c * EE;
        for (int k = 0; k < EE; k += 4) {
            float4 av = *(const float4*)(a + k);
            float4 wv = *(const float4*)(w + k);
            acc += av.x * wv.x + av.y * wv.y + av.z * wv.z + av.w * wv.w;
        }
        acc += ((const float*)bias)[c];
    } else {
        const unsigned* a = (const unsigned*)((const unsigned short*)emb + arow);
        const unsigned* w = (const unsigned*)((const unsigned short*)W + (size_t)c * EE);
        for (int k = 0; k < EE / 2; k += 4) {
            uint4 av = *(const uint4*)(a + k);
            uint4 wv = *(const uint4*)(w + k);
            acc += bflo(av.x) * bflo(wv.x) + bfhi(av.x) * bfhi(wv.x)
                 + bflo(av.y) * bflo(wv.y) + bfhi(av.y) * bfhi(wv.y)
                 + bflo(av.z) * bflo(wv.z) + bfhi(av.z) * bfhi(wv.z)
                 + bflo(av.w) * bflo(wv.w) + bfhi(av.w) * bfhi(wv.w);
        }
        acc += bf2f(((const unsigned short*)bias)[c]);
    }
    C[idx] = acc;
}

// Segment input GEMM: A = token-GRU outputs (fp32 ws, 1024 x 512)
__global__ __launch_bounds__(256) void gemm_out(const float* __restrict__ A,
                                                const void* __restrict__ W,
                                                const void* __restrict__ bias,
                                                float* __restrict__ C,
                                                const void* __restrict__ emb) {
    const int f32 = detect_f32(emb);
    int idx = blockIdx.x * 256 + threadIdx.x;
    int r = idx / G3, c = idx % G3;
    const float* a = A + (size_t)r * (2 * HH);
    float acc = 0.f;
    if (f32) {
        const float* w = (const float*)W + (size_t)c * (2 * HH);
        for (int k = 0; k < 2 * HH; k += 4) {
            float4 av = *(const float4*)(a + k);
            float4 wv = *(const float4*)(w + k);
            acc += av.x * wv.x + av.y * wv.y + av.z * wv.z + av.w * wv.w;
        }
        acc += ((const float*)bias)[c];
    } else {
        const unsigned* w = (const unsigned*)((const unsigned short*)W + (size_t)c * (2 * HH));
        for (int k = 0; k < HH; k += 4) {   // k counts uint pairs
            float4 a0 = *(const float4*)(a + 2 * k);
            float4 a1 = *(const float4*)(a + 2 * k + 4);
            uint4 wv = *(const uint4*)(w + k);
            acc += a0.x * bflo(wv.x) + a0.y * bfhi(wv.x)
                 + a0.z * bflo(wv.y) + a0.w * bfhi(wv.y)
                 + a1.x * bflo(wv.z) + a1.y * bfhi(wv.z)
                 + a1.z * bflo(wv.w) + a1.w * bfhi(wv.w);
        }
        acc += bf2f(((const unsigned short*)bias)[c]);
    }
    C[idx] = acc;
}

// ---------------------------------------------------------------------------
// Token-level bidirectional GRU scan (blocks 0,1) fused with d_out zero-fill
// (blocks 2..). 4 waves; each wave register-caches 192 cols of Wh as B-frags.
__global__ __launch_bounds__(256, 1) void token_scan_zero(
    const float* __restrict__ gi_f, const float* __restrict__ gi_r,
    const void* __restrict__ Wh_f, const void* __restrict__ Wh_r,
    const void* __restrict__ bh_f, const void* __restrict__ bh_r,
    float* __restrict__ outputs, void* __restrict__ dout,
    const void* __restrict__ emb) {

    const int f32 = detect_f32(emb);

    if (blockIdx.x >= 2) {
        uint4 z = {0u, 0u, 0u, 0u};
        uint4* p = (uint4*)dout;
        const size_t nvec = OUT_ELEMS * (f32 ? 4 : 2) / 16;
        size_t stride = (size_t)(gridDim.x - 2) * 256;
        for (size_t v = (size_t)(blockIdx.x - 2) * 256 + threadIdx.x; v < nvec; v += stride)
            p[v] = z;
        return;
    }

    const int dir = blockIdx.x;     // 0 = forward, 1 = reverse
    __shared__ float gh[BB][G3];
    __shared__ float hf[BB][HH];
    __shared__ __align__(16) unsigned short hb[16 * HBSTR];
    __shared__ float bhs[G3];

    const int tid = threadIdx.x;
    const int wave = tid >> 6, lane = tid & 63;
    const int l15 = lane & 15, quad = lane >> 4;

    const void* Wh = dir ? Wh_r : Wh_f;
    const void* bh = dir ? bh_r : bh_f;
    const float* gi = dir ? gi_r : gi_f;

    // B[k][n] = Wh[n][k]; lane holds n = l15 (per tile), k = quad*8..+7
    bf16x8 Bf[8][12];
#pragma unroll
    for (int nt = 0; nt < 12; ++nt) {
        int col = wave * 192 + nt * 16 + l15;
#pragma unroll
        for (int kt = 0; kt < 8; ++kt)
            Bf[kt][nt] = load8(Wh, (size_t)col * HH + kt * 32 + quad * 8, f32);
    }

    for (int e = tid; e < 16 * HBSTR; e += 256) hb[e] = 0;   // h0 = 0, pad 0
    for (int e = tid; e < BB * HH; e += 256) hf[e >> 8][e & 255] = 0.f;
    for (int c = tid; c < G3; c += 256) bhs[c] = lds1(bh, c, f32);
    __syncthreads();

    for (int t = 0; t < NN; ++t) {
        const int row = dir ? (NN - 1 - t) : t;
        f32x4 acc[12];
#pragma unroll
        for (int nt = 0; nt < 12; ++nt) acc[nt] = (f32x4){0.f, 0.f, 0.f, 0.f};
#pragma unroll
        for (int kt = 0; kt < 8; ++kt) {
            bf16x8 Af = *(const bf16x8*)(hb + l15 * HBSTR + kt * 32 + quad * 8);
#pragma unroll
            for (int nt = 0; nt < 12; ++nt)
                acc[nt] = __builtin_amdgcn_mfma_f32_16x16x32_bf16(Af, Bf[kt][nt], acc[nt], 0, 0, 0);
        }
        if (quad < 2) {
#pragma unroll
            for (int nt = 0; nt < 12; ++nt) {
                int col = wave * 192 + nt * 16 + l15;
#pragma unroll
                for (int r4 = 0; r4 < 4; ++r4) gh[quad * 4 + r4][col] = acc[nt][r4];
            }
        }
        __syncthreads();
#pragma unroll
        for (int b = 0; b < BB; ++b) {
            const int c = tid;
            const float* gp = gi + ((size_t)(row * BB + b)) * G3;
            float rr = sigm(gp[c] + gh[b][c] + bhs[c]);
            float zz = sigm(gp[c + 256] + gh[b][c + 256] + bhs[c + 256]);
            float nn = tanhf(gp[c + 512] + rr * (gh[b][c + 512] + bhs[c + 512]));
            float hn = (1.f - zz) * nn + zz * hf[b][c];
            hf[b][c] = hn;
            hb[b * HBSTR + c] = f2bf(hn);
            outputs[((size_t)(row * BB + b)) * 512 + dir * 256 + c] = hn;
        }
        __syncthreads();
    }
}

// ---------------------------------------------------------------------------
// Segment GRU scans: 256 blocks = (start i, dir). Writes band of dp_tri + hidden.
__global__ __launch_bounds__(256, 1) void seg_scan(
    const float* __restrict__ gi,              // gi_s (1024 x 768) fp32 ws
    const void* __restrict__ Wh,
    const void* __restrict__ bh,
    const void* __restrict__ h0f,
    const void* __restrict__ h0b,
    void* __restrict__ dout,
    const void* __restrict__ emb) {

    const int f32 = detect_f32(emb);

    __shared__ float gh[BB][G3];
    __shared__ float hf[BB][SS];
    __shared__ __align__(16) unsigned short hb[16 * HBSTR];
    __shared__ float bhs[G3];

    const int tid = threadIdx.x;
    const int wave = tid >> 6, lane = tid & 63;
    const int l15 = lane & 15, quad = lane >> 4;
    const int dir = blockIdx.x & 1, i0 = blockIdx.x >> 1;

    bf16x8 Bf[8][12];
#pragma unroll
    for (int nt = 0; nt < 12; ++nt) {
        int col = wave * 192 + nt * 16 + l15;
#pragma unroll
        for (int kt = 0; kt < 8; ++kt)
            Bf[kt][nt] = load8(Wh, (size_t)col * SS + kt * 32 + quad * 8, f32);
    }

    const void* h0 = dir ? h0b : h0f;
    const size_t h0base = (size_t)i0 * (BB * SS);
    for (int e = tid; e < BB * SS; e += 256) {
        int b = e >> 8, c = e & 255;
        float v = lds1(h0, h0base + e, f32);
        hf[b][c] = v;
        hb[b * HBSTR + c] = f2bf(v);
    }
    for (int e = 8 * HBSTR + tid; e < 16 * HBSTR; e += 256) hb[e] = 0;
    for (int c = tid; c < G3; c += 256) bhs[c] = lds1(bh, c, f32);
    __syncthreads();

    const int nsteps = dir ? min(TT, i0 + 1) : min(TT, NN - i0);
    for (int t = 0; t < nsteps; ++t) {
        const int j = dir ? (i0 - t) : (i0 + t);
        f32x4 acc[12];
#pragma unroll
        for (int nt = 0; nt < 12; ++nt) acc[nt] = (f32x4){0.f, 0.f, 0.f, 0.f};
#pragma unroll
        for (int kt = 0; kt < 8; ++kt) {
            bf16x8 Af = *(const bf16x8*)(hb + l15 * HBSTR + kt * 32 + quad * 8);
#pragma unroll
            for (int nt = 0; nt < 12; ++nt)
                acc[nt] = __builtin_amdgcn_mfma_f32_16x16x32_bf16(Af, Bf[kt][nt], acc[nt], 0, 0, 0);
        }
        if (quad < 2) {
#pragma unroll
            for (int nt = 0; nt < 12; ++nt) {
                int col = wave * 192 + nt * 16 + l15;
#pragma unroll
                for (int r4 = 0; r4 < 4; ++r4) gh[quad * 4 + r4][col] = acc[nt][r4];
            }
        }
        __syncthreads();

        const int r0 = dir ? j : i0;                 // triu pair (r0, c0), c0-r0 = t
        const size_t tri = (size_t)r0 * NN - (size_t)(r0 * (r0 - 1)) / 2 + t;
        const size_t obase = tri * (BB * 512) + (dir ? 256 : 0);

#pragma unroll
        for (int b = 0; b < BB; ++b) {
            const int c = tid;
            const float* gp = gi + ((size_t)(j * BB + b)) * G3;
            float rr = sigm(gp[c] + gh[b][c] + bhs[c]);
            float zz = sigm(gp[c + 256] + gh[b][c + 256] + bhs[c + 256]);
            float nn = tanhf(gp[c + 512] + rr * (gh[b][c + 512] + bhs[c + 512]));
            float hn = (1.f - zz) * nn + zz * hf[b][c];
            hf[b][c] = hn;
            hb[b * HBSTR + c] = f2bf(hn);
            outw(dout, obase + b * 512 + c, hn, f32);
            if (i0 == NN - 1) {
                if (dir == 0 && t == 0)      outw(dout, HIDOFF + b * 512 + c, hn, f32);
                if (dir == 1 && t == TT - 1) outw(dout, HIDOFF + 256 + b * 512 + c, hn, f32);
            }
        }
        __syncthreads();
    }
}

// ---------------------------------------------------------------------------
extern "C" void kernel_launch(void* const* d_in, const int* in_sizes, int n_in,
                              void* d_out, int out_size, void* d_ws, size_t ws_size,
                              hipStream_t stream) {
    const int* tokens = (const int*)d_in[0];
    const void* emb   = d_in[1];
    const void* Wi_f  = d_in[2];
    const void* Wh_f  = d_in[3];
    const void* bi_f  = d_in[4];
    const void* bh_f  = d_in[5];
    const void* Wi_r  = d_in[6];
    const void* Wh_r  = d_in[7];
    const void* bi_r  = d_in[8];
    const void* bh_r  = d_in[9];
    const void* Wi_s  = d_in[10];
    const void* Wh_s  = d_in[11];
    const void* bi_s  = d_in[12];
    const void* bh_s  = d_in[13];
    const void* h0f   = d_in[14];
    const void* h0b   = d_in[15];

    float* ws   = (float*)d_ws;
    float* gif  = ws;                     // 1024*768
    float* gir  = gif + 786432;           // 1024*768
    float* outp = gir + 786432;           // 1024*512
    float* gis  = gif;                    // aliases gif (dead after token scan)
    // peak ws = (786432*2 + 524288) * 4 B = 8 MB

    gemm_tok<<<dim3(3072), dim3(256), 0, stream>>>(tokens, emb, Wi_f, bi_f, gif);
    gemm_tok<<<dim3(3072), dim3(256), 0, stream>>>(tokens, emb, Wi_r, bi_r, gir);
    token_scan_zero<<<dim3(1024), dim3(256), 0, stream>>>(gif, gir, Wh_f, Wh_r,
                                                          bh_f, bh_r, outp, d_out, emb);
    gemm_out<<<dim3(3072), dim3(256), 0, stream>>>(outp, Wi_s, bi_s, gis, emb);
    seg_scan<<<dim3(256), dim3(256), 0, stream>>>(gis, Wh_s, bh_s, h0f, h0b, d_out, emb);
}

// Round 3
// 809.052 us; speedup vs baseline: 2.1204x; 2.1204x over previous
//
#include <hip/hip_runtime.h>
#include <cstdint>
#include <cstddef>

// Problem constants
#define NN 128   // seq len
#define BB 8     // batch
#define EE 256   // embed
#define HH 256   // hidden
#define SS 256   // segment dim
#define TT 32    // segment threshold
#define G3 768   // 3*H = 3*S
#define HBSTR 264           // LDS bf16 h row stride (pad 256->264, 16B-aligned)
#define HIDOFF 33816576ull  // 8256*8*512, start of `hidden` in d_out (elements)
#define OUT_ELEMS 33820672ull

typedef __attribute__((ext_vector_type(8))) short bf16x8;
typedef __attribute__((ext_vector_type(4))) float f32x4;

__device__ __forceinline__ float bf2f(unsigned short u) {
    union { unsigned u; float f; } v; v.u = ((unsigned)u) << 16; return v.f;
}
__device__ __forceinline__ float bflo(unsigned u) {
    union { unsigned u; float f; } v; v.u = u << 16; return v.f;
}
__device__ __forceinline__ float bfhi(unsigned u) {
    union { unsigned u; float f; } v; v.u = u & 0xffff0000u; return v.f;
}
__device__ __forceinline__ unsigned short f2bf(float f) {
    union { float f; unsigned u; } v; v.f = f;
    unsigned r = v.u + 0x7fffu + ((v.u >> 16) & 1u);   // RNE
    return (unsigned short)(r >> 16);
}
__device__ __forceinline__ float sigm(float x) { return 1.f / (1.f + __expf(-x)); }
__device__ __forceinline__ float tanh_fast(float x) {
    float xc = fminf(fmaxf(x, -10.f), 10.f);
    float e2 = __expf(2.f * xc);
    return (e2 - 1.f) / (e2 + 1.f);
}

// Detect whether float-typed inputs are physically fp32 (vs bf16).
// (Round-2 counters: fp32 confirmed — WRITE_SIZE matches 4-byte output.)
__device__ __forceinline__ int detect_f32(const void* emb) {
    const unsigned* w = (const unsigned*)emb;
    int bad = 0;
    for (int i = 0; i < 128; ++i) {
        unsigned u = w[i];
        bad |= (((u >> 7)  & 0xFFu) >= 0xC8u);
        bad |= (((u >> 23) & 0xFFu) >= 0xC8u);
    }
    return bad;
}

__device__ __forceinline__ float lds1(const void* p, size_t i, int f32) {
    return f32 ? ((const float*)p)[i] : bf2f(((const unsigned short*)p)[i]);
}
__device__ __forceinline__ bf16x8 load8(const void* p, size_t off, int f32) {
    bf16x8 r;
    if (f32) {
        const float* q = (const float*)p + off;
        float4 a = *(const float4*)q, b = *(const float4*)(q + 4);
        r[0] = (short)f2bf(a.x); r[1] = (short)f2bf(a.y);
        r[2] = (short)f2bf(a.z); r[3] = (short)f2bf(a.w);
        r[4] = (short)f2bf(b.x); r[5] = (short)f2bf(b.y);
        r[6] = (short)f2bf(b.z); r[7] = (short)f2bf(b.w);
    } else {
        r = *(const bf16x8*)((const unsigned short*)p + off);
    }
    return r;
}
__device__ __forceinline__ void outw(void* p, size_t i, float v, int f32) {
    if (f32) ((float*)p)[i] = v;
    else ((unsigned short*)p)[i] = f2bf(v);
}

// ---------------------------------------------------------------------------
// MFMA GEMM: C[r][c] = sum_k A[r][k]*W[c][k] + bias[c], rows=1024, cols=768.
// Block = 256 thr / 4 waves, tile M=64 x N=96, A staged bf16 in dynamic LDS.
// If tok != nullptr, A row r = emb[tok[r]] (gather); else A = fp32 ws rows.
// If W2 != nullptr, grid doubles: upper half uses W2/bias2/C2 (fwd+rev fuse).
template <int KK>
__global__ __launch_bounds__(256) void gemm_mfma(
    const int* __restrict__ tok, const void* __restrict__ Asrc,
    const void* __restrict__ W,  const void* __restrict__ bias,  float* __restrict__ C,
    const void* __restrict__ W2, const void* __restrict__ bias2, float* __restrict__ C2,
    const void* __restrict__ emb) {

    const int f32 = detect_f32(emb);
    extern __shared__ unsigned short As[];    // 64 x (KK+4)
    constexpr int KP = KK + 4;

    int bid = blockIdx.x;
    const void* Wp = W; const void* bp = bias; float* Cp = C;
    if (W2 && bid >= 128) { bid -= 128; Wp = W2; bp = bias2; Cp = C2; }
    const int mb = bid >> 3, nb = bid & 7;    // 16 m-blocks x 8 n-blocks

    const int tid = threadIdx.x, wave = tid >> 6, lane = tid & 63;
    const int l15 = lane & 15, quad = lane >> 4;

    for (int e = tid * 4; e < 64 * KK; e += 1024) {
        int r = e / KK, k = e % KK;           // 4 | KK so no row straddle
        int gr = mb * 64 + r;
        float4 v;
        if (tok) {
            size_t arow = (size_t)tok[gr] * EE;
            if (f32) v = *(const float4*)((const float*)Asrc + arow + k);
            else {
                uint2 u = *(const uint2*)((const unsigned short*)Asrc + arow + k);
                v.x = bflo(u.x); v.y = bfhi(u.x); v.z = bflo(u.y); v.w = bfhi(u.y);
            }
        } else {
            v = *(const float4*)((const float*)Asrc + (size_t)gr * KK + k);
        }
        unsigned short* d = As + r * KP + k;
        d[0] = f2bf(v.x); d[1] = f2bf(v.y); d[2] = f2bf(v.z); d[3] = f2bf(v.w);
    }
    __syncthreads();

    f32x4 acc[6];
#pragma unroll
    for (int nt = 0; nt < 6; ++nt) acc[nt] = (f32x4){0.f, 0.f, 0.f, 0.f};
#pragma unroll
    for (int kt = 0; kt < KK / 32; ++kt) {
        bf16x8 Af = *(const bf16x8*)(As + (wave * 16 + l15) * KP + kt * 32 + quad * 8);
#pragma unroll
        for (int nt = 0; nt < 6; ++nt) {
            int col = nb * 96 + nt * 16 + l15;
            bf16x8 Bfr = load8(Wp, (size_t)col * KK + kt * 32 + quad * 8, f32);
            acc[nt] = __builtin_amdgcn_mfma_f32_16x16x32_bf16(Af, Bfr, acc[nt], 0, 0, 0);
        }
    }
#pragma unroll
    for (int nt = 0; nt < 6; ++nt) {
        int col = nb * 96 + nt * 16 + l15;
        float bv = lds1(bp, col, f32);
#pragma unroll
        for (int r4 = 0; r4 < 4; ++r4) {
            int row = mb * 64 + wave * 16 + quad * 4 + r4;
            Cp[(size_t)row * G3 + col] = acc[nt][r4] + bv;
        }
    }
}

// ---------------------------------------------------------------------------
// Token-level bidirectional GRU scan (blocks 0,1) fused with d_out zero-fill
// (blocks 2..). 512 thr / 8 waves; wave caches 96 cols of Wh = Bf[8][6] (192 VGPR).
__global__ __launch_bounds__(512, 2) void token_scan_zero(
    const float* __restrict__ gi_f, const float* __restrict__ gi_r,
    const void* __restrict__ Wh_f, const void* __restrict__ Wh_r,
    const void* __restrict__ bh_f, const void* __restrict__ bh_r,
    float* __restrict__ outputs, void* __restrict__ dout,
    const void* __restrict__ emb) {

    const int f32 = detect_f32(emb);

    if (blockIdx.x >= 2) {
        uint4 z = {0u, 0u, 0u, 0u};
        uint4* p = (uint4*)dout;
        const size_t nvec = OUT_ELEMS * (f32 ? 4 : 2) / 16;
        size_t stride = (size_t)(gridDim.x - 2) * 512;
        for (size_t v = (size_t)(blockIdx.x - 2) * 512 + threadIdx.x; v < nvec; v += stride)
            p[v] = z;
        return;
    }

    const int dir = blockIdx.x;     // 0 = forward, 1 = reverse
    __shared__ float gh[BB][G3];
    __shared__ float hf[BB][HH];
    __shared__ __align__(16) unsigned short hb[16 * HBSTR];
    __shared__ float bhs[G3];

    const int tid = threadIdx.x;
    const int wave = tid >> 6, lane = tid & 63;
    const int l15 = lane & 15, quad = lane >> 4;

    const void* Wh = dir ? Wh_r : Wh_f;
    const void* bh = dir ? bh_r : bh_f;
    const float* gi = dir ? gi_r : gi_f;

    // B[k][n] = Wh[n][k]; lane holds n = l15 (per 16-col tile), k = quad*8..+7
    bf16x8 Bf[8][6];
#pragma unroll
    for (int nt = 0; nt < 6; ++nt) {
        int col = wave * 96 + nt * 16 + l15;
#pragma unroll
        for (int kt = 0; kt < 8; ++kt)
            Bf[kt][nt] = load8(Wh, (size_t)col * HH + kt * 32 + quad * 8, f32);
    }

    for (int e = tid; e < 16 * HBSTR; e += 512) hb[e] = 0;   // h0 = 0, pad 0
    for (int e = tid; e < BB * HH; e += 512) hf[e >> 8][e & 255] = 0.f;
    for (int c = tid; c < G3; c += 512) bhs[c] = lds1(bh, c, f32);
    __syncthreads();

    const int c = tid & 255, b0 = tid >> 8;
    for (int t = 0; t < NN; ++t) {
        const int row = dir ? (NN - 1 - t) : t;
        f32x4 acc[6];
#pragma unroll
        for (int nt = 0; nt < 6; ++nt) acc[nt] = (f32x4){0.f, 0.f, 0.f, 0.f};
#pragma unroll
        for (int kt = 0; kt < 8; ++kt) {
            bf16x8 Af = *(const bf16x8*)(hb + l15 * HBSTR + kt * 32 + quad * 8);
#pragma unroll
            for (int nt = 0; nt < 6; ++nt)
                acc[nt] = __builtin_amdgcn_mfma_f32_16x16x32_bf16(Af, Bf[kt][nt], acc[nt], 0, 0, 0);
        }
        if (quad < 2) {
#pragma unroll
            for (int nt = 0; nt < 6; ++nt) {
                int col = wave * 96 + nt * 16 + l15;
#pragma unroll
                for (int r4 = 0; r4 < 4; ++r4) gh[quad * 4 + r4][col] = acc[nt][r4];
            }
        }
        __syncthreads();
#pragma unroll
        for (int q = 0; q < 4; ++q) {
            const int b = q * 2 + b0;
            const float* gp = gi + ((size_t)(row * BB + b)) * G3;
            float rr = sigm(gp[c] + gh[b][c] + bhs[c]);
            float zz = sigm(gp[c + 256] + gh[b][c + 256] + bhs[c + 256]);
            float nn = tanh_fast(gp[c + 512] + rr * (gh[b][c + 512] + bhs[c + 512]));
            float hn = (1.f - zz) * nn + zz * hf[b][c];
            hf[b][c] = hn;
            hb[b * HBSTR + c] = f2bf(hn);
            outputs[((size_t)(row * BB + b)) * 512 + dir * 256 + c] = hn;
        }
        __syncthreads();
    }
}

// ---------------------------------------------------------------------------
// Segment GRU scans: 256 blocks = (start i, dir), 512 threads each.
__global__ __launch_bounds__(512, 2) void seg_scan(
    const float* __restrict__ gi,              // gi_s (1024 x 768) fp32 ws
    const void* __restrict__ Wh,
    const void* __restrict__ bh,
    const void* __restrict__ h0f,
    const void* __restrict__ h0b,
    void* __restrict__ dout,
    const void* __restrict__ emb) {

    const int f32 = detect_f32(emb);

    __shared__ float gh[BB][G3];
    __shared__ float hf[BB][SS];
    __shared__ __align__(16) unsigned short hb[16 * HBSTR];
    __shared__ float bhs[G3];

    const int tid = threadIdx.x;
    const int wave = tid >> 6, lane = tid & 63;
    const int l15 = lane & 15, quad = lane >> 4;
    const int dir = blockIdx.x & 1, i0 = blockIdx.x >> 1;

    bf16x8 Bf[8][6];
#pragma unroll
    for (int nt = 0; nt < 6; ++nt) {
        int col = wave * 96 + nt * 16 + l15;
#pragma unroll
        for (int kt = 0; kt < 8; ++kt)
            Bf[kt][nt] = load8(Wh, (size_t)col * SS + kt * 32 + quad * 8, f32);
    }

    const void* h0 = dir ? h0b : h0f;
    const size_t h0base = (size_t)i0 * (BB * SS);
    for (int e = tid; e < BB * SS; e += 512) {
        int b = e >> 8, cc = e & 255;
        float v = lds1(h0, h0base + e, f32);
        hf[b][cc] = v;
        hb[b * HBSTR + cc] = f2bf(v);
    }
    for (int e = 8 * HBSTR + tid; e < 16 * HBSTR; e += 512) hb[e] = 0;
    for (int cc = tid; cc < G3; cc += 512) bhs[cc] = lds1(bh, cc, f32);
    __syncthreads();

    const int c = tid & 255, b0 = tid >> 8;
    const int nsteps = dir ? min(TT, i0 + 1) : min(TT, NN - i0);
    for (int t = 0; t < nsteps; ++t) {
        const int j = dir ? (i0 - t) : (i0 + t);
        f32x4 acc[6];
#pragma unroll
        for (int nt = 0; nt < 6; ++nt) acc[nt] = (f32x4){0.f, 0.f, 0.f, 0.f};
#pragma unroll
        for (int kt = 0; kt < 8; ++kt) {
            bf16x8 Af = *(const bf16x8*)(hb + l15 * HBSTR + kt * 32 + quad * 8);
#pragma unroll
            for (int nt = 0; nt < 6; ++nt)
                acc[nt] = __builtin_amdgcn_mfma_f32_16x16x32_bf16(Af, Bf[kt][nt], acc[nt], 0, 0, 0);
        }
        if (quad < 2) {
#pragma unroll
            for (int nt = 0; nt < 6; ++nt) {
                int col = wave * 96 + nt * 16 + l15;
#pragma unroll
                for (int r4 = 0; r4 < 4; ++r4) gh[quad * 4 + r4][col] = acc[nt][r4];
            }
        }
        __syncthreads();

        const int r0 = dir ? j : i0;                 // triu pair (r0, c0), c0-r0 = t
        const size_t tri = (size_t)r0 * NN - (size_t)(r0 * (r0 - 1)) / 2 + t;
        const size_t obase = tri * (BB * 512) + (dir ? 256 : 0);

#pragma unroll
        for (int q = 0; q < 4; ++q) {
            const int b = q * 2 + b0;
            const float* gp = gi + ((size_t)(j * BB + b)) * G3;
            float rr = sigm(gp[c] + gh[b][c] + bhs[c]);
            float zz = sigm(gp[c + 256] + gh[b][c + 256] + bhs[c + 256]);
            float nn = tanh_fast(gp[c + 512] + rr * (gh[b][c + 512] + bhs[c + 512]));
            float hn = (1.f - zz) * nn + zz * hf[b][c];
            hf[b][c] = hn;
            hb[b * HBSTR + c] = f2bf(hn);
            outw(dout, obase + b * 512 + c, hn, f32);
            if (i0 == NN - 1) {
                if (dir == 0 && t == 0)      outw(dout, HIDOFF + b * 512 + c, hn, f32);
                if (dir == 1 && t == TT - 1) outw(dout, HIDOFF + 256 + b * 512 + c, hn, f32);
            }
        }
        __syncthreads();
    }
}

// ---------------------------------------------------------------------------
extern "C" void kernel_launch(void* const* d_in, const int* in_sizes, int n_in,
                              void* d_out, int out_size, void* d_ws, size_t ws_size,
                              hipStream_t stream) {
    const int* tokens = (const int*)d_in[0];
    const void* emb   = d_in[1];
    const void* Wi_f  = d_in[2];
    const void* Wh_f  = d_in[3];
    const void* bi_f  = d_in[4];
    const void* bh_f  = d_in[5];
    const void* Wi_r  = d_in[6];
    const void* Wh_r  = d_in[7];
    const void* bi_r  = d_in[8];
    const void* bh_r  = d_in[9];
    const void* Wi_s  = d_in[10];
    const void* Wh_s  = d_in[11];
    const void* bi_s  = d_in[12];
    const void* bh_s  = d_in[13];
    const void* h0f   = d_in[14];
    const void* h0b   = d_in[15];

    float* ws   = (float*)d_ws;
    float* gif  = ws;                     // 1024*768
    float* gir  = gif + 786432;           // 1024*768
    float* outp = gir + 786432;           // 1024*512
    float* gis  = gif;                    // aliases gif (dead after token scan)
    // peak ws = (786432*2 + 524288) * 4 B = 8 MB

    // fused fwd+rev token-gate GEMMs (grid halves select weight set)
    gemm_mfma<256><<<dim3(256), dim3(256), (256 + 4) * 64 * 2, stream>>>(
        tokens, emb, Wi_f, bi_f, gif, Wi_r, bi_r, gir, emb);
    token_scan_zero<<<dim3(1024), dim3(512), 0, stream>>>(gif, gir, Wh_f, Wh_r,
                                                          bh_f, bh_r, outp, d_out, emb);
    gemm_mfma<512><<<dim3(128), dim3(256), (512 + 4) * 64 * 2, stream>>>(
        nullptr, outp, Wi_s, bi_s, gis, nullptr, nullptr, nullptr, emb);
    seg_scan<<<dim3(256), dim3(512), 0, stream>>>(gis, Wh_s, bh_s, h0f, h0b, d_out, emb);
}

// Round 4
// 747.325 us; speedup vs baseline: 2.2955x; 1.0826x over previous
//
#include <hip/hip_runtime.h>
#include <cstdint>
#include <cstddef>

// Problem constants
#define NN 128   // seq len
#define BB 8     // batch
#define EE 256   // embed
#define HH 256   // hidden
#define SS 256   // segment dim
#define TT 32    // segment threshold
#define G3 768   // 3*H = 3*S
#define HBSTR 264           // LDS bf16 h row stride (pad 256->264)
#define HIDOFF 33816576ull  // 8256*8*512, start of `hidden` in d_out (elements)
#define OUT_ELEMS 33820672ull

typedef __attribute__((ext_vector_type(8))) short bf16x8;
typedef __attribute__((ext_vector_type(4))) float f32x4;

__device__ __forceinline__ float bf2f(unsigned short u) {
    union { unsigned u; float f; } v; v.u = ((unsigned)u) << 16; return v.f;
}
__device__ __forceinline__ unsigned short f2bf(float f) {
    union { float f; unsigned u; } v; v.f = f;
    unsigned r = v.u + 0x7fffu + ((v.u >> 16) & 1u);   // RNE
    return (unsigned short)(r >> 16);
}
__device__ __forceinline__ float sigm(float x) { return 1.f / (1.f + __expf(-x)); }
__device__ __forceinline__ float tanh_fast(float x) {
    float xc = fminf(fmaxf(x, -10.f), 10.f);
    float e2 = __expf(2.f * xc);
    return (e2 - 1.f) / (e2 + 1.f);
}

// fp32-vs-bf16 physical layout detector (round-2 counters: fp32 confirmed).
__device__ __forceinline__ int detect_f32(const void* emb) {
    const unsigned* w = (const unsigned*)emb;
    int bad = 0;
    for (int i = 0; i < 128; ++i) {
        unsigned u = w[i];
        bad |= (((u >> 7)  & 0xFFu) >= 0xC8u);
        bad |= (((u >> 23) & 0xFFu) >= 0xC8u);
    }
    return bad;
}
__device__ __forceinline__ float lds1(const void* p, size_t i, int f32) {
    return f32 ? ((const float*)p)[i] : bf2f(((const unsigned short*)p)[i]);
}
__device__ __forceinline__ void outw(void* p, size_t i, float v, int f32) {
    if (f32) ((float*)p)[i] = v;
    else ((unsigned short*)p)[i] = f2bf(v);
}

// ---------------------------------------------------------------------------
// One-shot weight conversion to bf16 in ws. Layout (ushort offsets):
// Wi_f 0, Wi_r 196608, Wh_f 393216, Wh_r 589824, Wh_s 786432, Wi_s 983040 (x393216)
__global__ __launch_bounds__(256) void conv_all(
    const void* __restrict__ Wi_f, const void* __restrict__ Wi_r,
    const void* __restrict__ Wh_f, const void* __restrict__ Wh_r,
    const void* __restrict__ Wh_s, const void* __restrict__ Wi_s,
    unsigned short* __restrict__ dst, const void* __restrict__ emb) {
    const int f32 = detect_f32(emb);
    size_t i = ((size_t)blockIdx.x * 256 + threadIdx.x) * 8;   // grid 672 blocks
    const void* src; size_t off;
    if      (i < 196608)  { src = Wi_f; off = i; }
    else if (i < 393216)  { src = Wi_r; off = i - 196608; }
    else if (i < 589824)  { src = Wh_f; off = i - 393216; }
    else if (i < 786432)  { src = Wh_r; off = i - 589824; }
    else if (i < 983040)  { src = Wh_s; off = i - 786432; }
    else                  { src = Wi_s; off = i - 983040; }
    bf16x8 v;
    if (f32) {
        const float* q = (const float*)src + off;
        float4 a = *(const float4*)q, b = *(const float4*)(q + 4);
        v[0] = (short)f2bf(a.x); v[1] = (short)f2bf(a.y);
        v[2] = (short)f2bf(a.z); v[3] = (short)f2bf(a.w);
        v[4] = (short)f2bf(b.x); v[5] = (short)f2bf(b.y);
        v[6] = (short)f2bf(b.z); v[7] = (short)f2bf(b.w);
    } else {
        v = *(const bf16x8*)((const unsigned short*)src + off);
    }
    *(bf16x8*)(dst + i) = v;
}

// ---------------------------------------------------------------------------
// MFMA GEMM, W pre-converted bf16. C bf16. A: token-gather (emb) or bf16 ws.
template <int KK>
__global__ __launch_bounds__(256) void gemm_mfma(
    const int* __restrict__ tok, const void* __restrict__ Asrc,
    const unsigned short* __restrict__ W,  const void* __restrict__ bias,
    unsigned short* __restrict__ C,
    const unsigned short* __restrict__ W2, const void* __restrict__ bias2,
    unsigned short* __restrict__ C2, const void* __restrict__ emb) {

    const int f32 = detect_f32(emb);
    __shared__ unsigned short As[64 * 260];

    int bid = blockIdx.x;
    const unsigned short* Wp = W; const void* bp = bias; unsigned short* Cp = C;
    if (C2 && bid >= 128) { bid -= 128; Wp = W2; bp = bias2; Cp = C2; }
    const int mb = bid >> 3, nb = bid & 7;

    const int tid = threadIdx.x, wave = tid >> 6, lane = tid & 63;
    const int l15 = lane & 15, quad = lane >> 4;

    f32x4 acc[6];
#pragma unroll
    for (int nt = 0; nt < 6; ++nt) acc[nt] = (f32x4){0.f, 0.f, 0.f, 0.f};

    for (int kh = 0; kh < KK; kh += 256) {
        __syncthreads();
        for (int e = tid * 4; e < 64 * 256; e += 1024) {
            int r = e >> 8, k = e & 255;
            int gr = mb * 64 + r;
            unsigned short h4[4];
            if (tok) {
                size_t arow = (size_t)tok[gr] * EE + kh + k;
                if (f32) {
                    float4 v = *(const float4*)((const float*)Asrc + arow);
                    h4[0] = f2bf(v.x); h4[1] = f2bf(v.y); h4[2] = f2bf(v.z); h4[3] = f2bf(v.w);
                } else {
                    *(uint2*)h4 = *(const uint2*)((const unsigned short*)Asrc + arow);
                }
            } else {
                *(uint2*)h4 = *(const uint2*)((const unsigned short*)Asrc + (size_t)gr * KK + kh + k);
            }
            *(uint2*)(As + r * 260 + k) = *(uint2*)h4;
        }
        __syncthreads();
#pragma unroll
        for (int kt = 0; kt < 8; ++kt) {
            bf16x8 Af = *(const bf16x8*)(As + (wave * 16 + l15) * 260 + kt * 32 + quad * 8);
#pragma unroll
            for (int nt = 0; nt < 6; ++nt) {
                int col = nb * 96 + nt * 16 + l15;
                bf16x8 Bfr = *(const bf16x8*)(Wp + (size_t)col * KK + kh + kt * 32 + quad * 8);
                acc[nt] = __builtin_amdgcn_mfma_f32_16x16x32_bf16(Af, Bfr, acc[nt], 0, 0, 0);
            }
        }
    }
#pragma unroll
    for (int nt = 0; nt < 6; ++nt) {
        int col = nb * 96 + nt * 16 + l15;
        float bv = lds1(bp, col, f32);
#pragma unroll
        for (int r4 = 0; r4 < 4; ++r4) {
            int row = mb * 64 + wave * 16 + quad * 4 + r4;
            Cp[(size_t)row * G3 + col] = f2bf(acc[nt][r4] + bv);
        }
    }
}

// ---------------------------------------------------------------------------
// Shared GRU-step machinery for the scan kernels. 256 thr / 4 waves; each wave
// owns 192 cols: 96 B-frags = 64 AGPR-pinned + 32 VGPR-pinned (no remat!).
#define LOAD_BFRAGS(Whc)                                                        \
    bf16x8 Ba[8][8]; bf16x8 Bv[8][4];                                           \
    _Pragma("unroll")                                                           \
    for (int nt = 0; nt < 12; ++nt) {                                           \
        int col = wave * 192 + nt * 16 + l15;                                   \
        _Pragma("unroll")                                                       \
        for (int kt = 0; kt < 8; ++kt) {                                        \
            bf16x8 f = *(const bf16x8*)(Whc + (size_t)col * 256 + kt * 32 + quad * 8); \
            if (nt < 8) Ba[kt][nt] = f; else Bv[kt][nt - 8] = f;                \
        }                                                                       \
    }                                                                           \
    _Pragma("unroll")                                                           \
    for (int kt = 0; kt < 8; ++kt) {                                            \
        _Pragma("unroll")                                                       \
        for (int nt = 0; nt < 8; ++nt) asm volatile("" : "+a"(Ba[kt][nt]));     \
        _Pragma("unroll")                                                       \
        for (int nt = 0; nt < 4; ++nt) asm volatile("" : "+v"(Bv[kt][nt]));     \
    }

#define MFMA_GH()                                                               \
    {                                                                           \
        f32x4 acc[12];                                                          \
        _Pragma("unroll")                                                       \
        for (int nt = 0; nt < 12; ++nt) acc[nt] = (f32x4){0.f, 0.f, 0.f, 0.f};  \
        _Pragma("unroll")                                                       \
        for (int kt = 0; kt < 8; ++kt) {                                        \
            bf16x8 Af = *(const bf16x8*)(hb + l15 * HBSTR + kt * 32 + quad * 8);\
            _Pragma("unroll")                                                   \
            for (int nt = 0; nt < 8; ++nt)                                      \
                acc[nt] = __builtin_amdgcn_mfma_f32_16x16x32_bf16(Af, Ba[kt][nt], acc[nt], 0, 0, 0); \
            _Pragma("unroll")                                                   \
            for (int nt = 0; nt < 4; ++nt)                                      \
                acc[8 + nt] = __builtin_amdgcn_mfma_f32_16x16x32_bf16(Af, Bv[kt][nt], acc[8 + nt], 0, 0, 0); \
        }                                                                       \
        if (quad < 2) {                                                         \
            _Pragma("unroll")                                                   \
            for (int nt = 0; nt < 12; ++nt) {                                   \
                int col = wave * 192 + nt * 16 + l15;                           \
                _Pragma("unroll")                                               \
                for (int r4 = 0; r4 < 4; ++r4) gh[quad * 4 + r4][col] = acc[nt][r4]; \
            }                                                                   \
        }                                                                       \
    }

// ---------------------------------------------------------------------------
// Token bidirectional GRU scan (blocks 0,1) + d_out zero-fill (blocks 2..255).
__global__ __attribute__((amdgpu_flat_work_group_size(256, 256), amdgpu_waves_per_eu(1, 1)))
void token_scan_zero(
    const unsigned short* __restrict__ gi_f, const unsigned short* __restrict__ gi_r,
    const unsigned short* __restrict__ Wh_fc, const unsigned short* __restrict__ Wh_rc,
    const void* __restrict__ bh_f, const void* __restrict__ bh_r,
    unsigned short* __restrict__ outp, void* __restrict__ dout,
    const void* __restrict__ emb) {

    const int f32 = detect_f32(emb);

    if (blockIdx.x >= 2) {
        uint4 z = {0u, 0u, 0u, 0u};
        uint4* p = (uint4*)dout;
        const size_t nvec = OUT_ELEMS * (f32 ? 4 : 2) / 16;
        size_t stride = (size_t)(gridDim.x - 2) * 256;
        for (size_t v = (size_t)(blockIdx.x - 2) * 256 + threadIdx.x; v < nvec; v += stride)
            p[v] = z;
        return;
    }

    const int dir = blockIdx.x;
    __shared__ float gh[BB][G3];
    __shared__ __align__(16) unsigned short hb[16 * HBSTR];
    __shared__ float bhs[G3];

    const int tid = threadIdx.x;
    const int wave = tid >> 6, lane = tid & 63;
    const int l15 = lane & 15, quad = lane >> 4;

    const unsigned short* Whc = dir ? Wh_rc : Wh_fc;
    const void* bh = dir ? bh_r : bh_f;
    const unsigned short* gi = dir ? gi_r : gi_f;

    LOAD_BFRAGS(Whc)

    for (int e = tid; e < 16 * HBSTR; e += 256) hb[e] = 0;    // h0 = 0, pads 0
    for (int c2 = tid; c2 < G3; c2 += 256) bhs[c2] = lds1(bh, c2, f32);
    float hreg[BB];
#pragma unroll
    for (int b = 0; b < BB; ++b) hreg[b] = 0.f;
    __syncthreads();

    const int c = tid;
    for (int t = 0; t < NN; ++t) {
        const int row = dir ? (NN - 1 - t) : t;
        // prefetch gi row (independent of MFMA phase -> latency hidden)
        unsigned short gpre[BB][3];
        const unsigned short* gp = gi + (size_t)row * BB * G3;
#pragma unroll
        for (int b = 0; b < BB; ++b) {
            gpre[b][0] = gp[b * G3 + c];
            gpre[b][1] = gp[b * G3 + c + 256];
            gpre[b][2] = gp[b * G3 + c + 512];
        }
        MFMA_GH()
        __syncthreads();
#pragma unroll
        for (int b = 0; b < BB; ++b) {
            float rr = sigm(bf2f(gpre[b][0]) + gh[b][c] + bhs[c]);
            float zz = sigm(bf2f(gpre[b][1]) + gh[b][c + 256] + bhs[c + 256]);
            float nn = tanh_fast(bf2f(gpre[b][2]) + rr * (gh[b][c + 512] + bhs[c + 512]));
            float hn = (1.f - zz) * nn + zz * hreg[b];
            hreg[b] = hn;
            unsigned short hu = f2bf(hn);
            hb[b * HBSTR + c] = hu;
            outp[((size_t)(row * BB + b)) * 512 + dir * 256 + c] = hu;
        }
        __syncthreads();
    }
}

// ---------------------------------------------------------------------------
// Segment GRU scans: 256 blocks = (start i0, dir), 256 threads, 1 block/CU.
__global__ __attribute__((amdgpu_flat_work_group_size(256, 256), amdgpu_waves_per_eu(1, 1)))
void seg_scan(
    const unsigned short* __restrict__ gi,     // gi_s bf16 ws (1024 x 768)
    const unsigned short* __restrict__ Whc,    // Wh_s bf16 ws
    const void* __restrict__ bh,
    const void* __restrict__ h0f, const void* __restrict__ h0b,
    void* __restrict__ dout, const void* __restrict__ emb) {

    const int f32 = detect_f32(emb);

    __shared__ float gh[BB][G3];
    __shared__ __align__(16) unsigned short hb[16 * HBSTR];
    __shared__ float bhs[G3];

    const int tid = threadIdx.x;
    const int wave = tid >> 6, lane = tid & 63;
    const int l15 = lane & 15, quad = lane >> 4;
    const int dir = blockIdx.x & 1, i0 = blockIdx.x >> 1;

    LOAD_BFRAGS(Whc)

    const void* h0 = dir ? h0b : h0f;
    const size_t h0base = (size_t)i0 * (BB * SS);
    const int c = tid;
    float hreg[BB];
#pragma unroll
    for (int b = 0; b < BB; ++b) {
        float v = lds1(h0, h0base + b * 256 + c, f32);
        hreg[b] = v;
        hb[b * HBSTR + c] = f2bf(v);
    }
    for (int e = 8 * HBSTR + tid; e < 16 * HBSTR; e += 256) hb[e] = 0;
    for (int c2 = tid; c2 < G3; c2 += 256) bhs[c2] = lds1(bh, c2, f32);
    __syncthreads();

    const int nsteps = dir ? min(TT, i0 + 1) : min(TT, NN - i0);
    for (int t = 0; t < nsteps; ++t) {
        const int j = dir ? (i0 - t) : (i0 + t);
        unsigned short gpre[BB][3];
        const unsigned short* gp = gi + (size_t)j * BB * G3;
#pragma unroll
        for (int b = 0; b < BB; ++b) {
            gpre[b][0] = gp[b * G3 + c];
            gpre[b][1] = gp[b * G3 + c + 256];
            gpre[b][2] = gp[b * G3 + c + 512];
        }
        MFMA_GH()
        __syncthreads();

        const int r0 = dir ? j : i0;                 // triu pair (r0,c0), c0-r0=t
        const size_t tri = (size_t)r0 * NN - (size_t)(r0 * (r0 - 1)) / 2 + t;
        const size_t obase = tri * (BB * 512) + (dir ? 256 : 0);

#pragma unroll
        for (int b = 0; b < BB; ++b) {
            float rr = sigm(bf2f(gpre[b][0]) + gh[b][c] + bhs[c]);
            float zz = sigm(bf2f(gpre[b][1]) + gh[b][c + 256] + bhs[c + 256]);
            float nn = tanh_fast(bf2f(gpre[b][2]) + rr * (gh[b][c + 512] + bhs[c + 512]));
            float hn = (1.f - zz) * nn + zz * hreg[b];
            hreg[b] = hn;
            hb[b * HBSTR + c] = f2bf(hn);
            outw(dout, obase + b * 512 + c, hn, f32);
            if (i0 == NN - 1) {
                if (dir == 0 && t == 0)      outw(dout, HIDOFF + b * 512 + c, hn, f32);
                if (dir == 1 && t == TT - 1) outw(dout, HIDOFF + 256 + b * 512 + c, hn, f32);
            }
        }
        __syncthreads();
    }
}

// ---------------------------------------------------------------------------
extern "C" void kernel_launch(void* const* d_in, const int* in_sizes, int n_in,
                              void* d_out, int out_size, void* d_ws, size_t ws_size,
                              hipStream_t stream) {
    const int* tokens = (const int*)d_in[0];
    const void* emb   = d_in[1];
    const void* Wi_f  = d_in[2];
    const void* Wh_f  = d_in[3];
    const void* bi_f  = d_in[4];
    const void* bh_f  = d_in[5];
    const void* Wi_r  = d_in[6];
    const void* Wh_r  = d_in[7];
    const void* bi_r  = d_in[8];
    const void* bh_r  = d_in[9];
    const void* Wi_s  = d_in[10];
    const void* Wh_s  = d_in[11];
    const void* bi_s  = d_in[12];
    const void* bh_s  = d_in[13];
    const void* h0f   = d_in[14];
    const void* h0b   = d_in[15];

    unsigned short* wsu = (unsigned short*)d_ws;
    unsigned short* gif  = wsu;                 // 786432 halves (1.5 MB)
    unsigned short* gir  = wsu + 786432;        // 786432
    unsigned short* outp = wsu + 1572864;       // 524288 (1 MB)
    unsigned short* wcv  = wsu + 2097152;       // 1376256 (2.625 MB)
    unsigned short* gis  = gif;                 // alias (gif dead after token scan)
    // peak ws = 6.63 MB (< 8 MB proven in rounds 2-3)

    const unsigned short* Wi_fc = wcv;
    const unsigned short* Wi_rc = wcv + 196608;
    const unsigned short* Wh_fc = wcv + 393216;
    const unsigned short* Wh_rc = wcv + 589824;
    const unsigned short* Wh_sc = wcv + 786432;
    const unsigned short* Wi_sc = wcv + 983040;

    conv_all<<<dim3(672), dim3(256), 0, stream>>>(Wi_f, Wi_r, Wh_f, Wh_r, Wh_s, Wi_s,
                                                  wcv, emb);
    gemm_mfma<256><<<dim3(256), dim3(256), 0, stream>>>(
        tokens, emb, Wi_fc, bi_f, gif, Wi_rc, bi_r, gir, emb);
    token_scan_zero<<<dim3(256), dim3(256), 0, stream>>>(gif, gir, Wh_fc, Wh_rc,
                                                         bh_f, bh_r, outp, d_out, emb);
    gemm_mfma<512><<<dim3(128), dim3(256), 0, stream>>>(
        nullptr, outp, Wi_sc, bi_s, gis, nullptr, nullptr, nullptr, emb);
    seg_scan<<<dim3(256), dim3(256), 0, stream>>>(gis, Wh_sc, bh_s, h0f, h0b, d_out, emb);
}

// Round 6
// 668.917 us; speedup vs baseline: 2.5646x; 1.1172x over previous
//
#include <hip/hip_runtime.h>
#include <cstdint>
#include <cstddef>

// Problem constants
#define NN 128   // seq len
#define BB 8     // batch
#define EE 256   // embed
#define HH 256   // hidden
#define SS 256   // segment dim
#define TT 32    // segment threshold
#define G3 768   // 3*H = 3*S
#define HBSTR 264           // LDS bf16 h row stride (pad 256->264)
#define HIDOFF 33816576ull  // 8256*8*512, start of `hidden` in d_out (elements)
#define OUT_ELEMS 33820672ull

typedef __attribute__((ext_vector_type(8))) short bf16x8;
typedef __attribute__((ext_vector_type(4))) float f32x4;

__device__ __forceinline__ float bf2f(unsigned short u) {
    union { unsigned u; float f; } v; v.u = ((unsigned)u) << 16; return v.f;
}
__device__ __forceinline__ unsigned short f2bf(float f) {
    union { float f; unsigned u; } v; v.f = f;
    unsigned r = v.u + 0x7fffu + ((v.u >> 16) & 1u);   // RNE
    return (unsigned short)(r >> 16);
}
__device__ __forceinline__ float rcpf(float x) { return __builtin_amdgcn_rcpf(x); }
__device__ __forceinline__ float sigm(float x) { return rcpf(1.f + __expf(-x)); }
__device__ __forceinline__ float tanh_fast(float x) {
    float xc = fminf(fmaxf(x, -10.f), 10.f);
    float e2 = __expf(2.f * xc);
    return (e2 - 1.f) * rcpf(e2 + 1.f);
}

// fp32-vs-bf16 physical layout detector (round-2 counters: fp32 confirmed).
__device__ __forceinline__ int detect_f32(const void* emb) {
    const unsigned* w = (const unsigned*)emb;
    int bad = 0;
    for (int i = 0; i < 128; ++i) {
        unsigned u = w[i];
        bad |= (((u >> 7)  & 0xFFu) >= 0xC8u);
        bad |= (((u >> 23) & 0xFFu) >= 0xC8u);
    }
    return bad;
}
__device__ __forceinline__ float lds1(const void* p, size_t i, int f32) {
    return f32 ? ((const float*)p)[i] : bf2f(((const unsigned short*)p)[i]);
}
__device__ __forceinline__ void outw(void* p, size_t i, float v, int f32) {
    if (f32) ((float*)p)[i] = v;
    else ((unsigned short*)p)[i] = f2bf(v);
}

// ---------------------------------------------------------------------------
// One-shot weight conversion to bf16 in ws. Layout (ushort offsets):
// Wi_f 0, Wi_r 196608, Wh_f 393216, Wh_r 589824, Wh_s 786432, Wi_s 983040 (x393216)
__global__ __launch_bounds__(256) void conv_all(
    const void* __restrict__ Wi_f, const void* __restrict__ Wi_r,
    const void* __restrict__ Wh_f, const void* __restrict__ Wh_r,
    const void* __restrict__ Wh_s, const void* __restrict__ Wi_s,
    unsigned short* __restrict__ dst, const void* __restrict__ emb) {
    const int f32 = detect_f32(emb);
    size_t i = ((size_t)blockIdx.x * 256 + threadIdx.x) * 8;   // grid 672 blocks
    const void* src; size_t off;
    if      (i < 196608)  { src = Wi_f; off = i; }
    else if (i < 393216)  { src = Wi_r; off = i - 196608; }
    else if (i < 589824)  { src = Wh_f; off = i - 393216; }
    else if (i < 786432)  { src = Wh_r; off = i - 589824; }
    else if (i < 983040)  { src = Wh_s; off = i - 786432; }
    else                  { src = Wi_s; off = i - 983040; }
    bf16x8 v;
    if (f32) {
        const float* q = (const float*)src + off;
        float4 a = *(const float4*)q, b = *(const float4*)(q + 4);
        v[0] = (short)f2bf(a.x); v[1] = (short)f2bf(a.y);
        v[2] = (short)f2bf(a.z); v[3] = (short)f2bf(a.w);
        v[4] = (short)f2bf(b.x); v[5] = (short)f2bf(b.y);
        v[6] = (short)f2bf(b.z); v[7] = (short)f2bf(b.w);
    } else {
        v = *(const bf16x8*)((const unsigned short*)src + off);
    }
    *(bf16x8*)(dst + i) = v;
}

// ---------------------------------------------------------------------------
// MFMA GEMM, W pre-converted bf16. C bf16. A: token-gather (emb) or bf16 ws.
template <int KK>
__global__ __launch_bounds__(256) void gemm_mfma(
    const int* __restrict__ tok, const void* __restrict__ Asrc,
    const unsigned short* __restrict__ W,  const void* __restrict__ bias,
    unsigned short* __restrict__ C,
    const unsigned short* __restrict__ W2, const void* __restrict__ bias2,
    unsigned short* __restrict__ C2, const void* __restrict__ emb) {

    const int f32 = detect_f32(emb);
    __shared__ unsigned short As[64 * 260];

    int bid = blockIdx.x;
    const unsigned short* Wp = W; const void* bp = bias; unsigned short* Cp = C;
    if (C2 && bid >= 128) { bid -= 128; Wp = W2; bp = bias2; Cp = C2; }
    const int mb = bid >> 3, nb = bid & 7;

    const int tid = threadIdx.x, wave = tid >> 6, lane = tid & 63;
    const int l15 = lane & 15, quad = lane >> 4;

    f32x4 acc[6];
#pragma unroll
    for (int nt = 0; nt < 6; ++nt) acc[nt] = (f32x4){0.f, 0.f, 0.f, 0.f};

    for (int kh = 0; kh < KK; kh += 256) {
        __syncthreads();
        for (int e = tid * 4; e < 64 * 256; e += 1024) {
            int r = e >> 8, k = e & 255;
            int gr = mb * 64 + r;
            unsigned short h4[4];
            if (tok) {
                size_t arow = (size_t)tok[gr] * EE + kh + k;
                if (f32) {
                    float4 v = *(const float4*)((const float*)Asrc + arow);
                    h4[0] = f2bf(v.x); h4[1] = f2bf(v.y); h4[2] = f2bf(v.z); h4[3] = f2bf(v.w);
                } else {
                    *(uint2*)h4 = *(const uint2*)((const unsigned short*)Asrc + arow);
                }
            } else {
                *(uint2*)h4 = *(const uint2*)((const unsigned short*)Asrc + (size_t)gr * KK + kh + k);
            }
            *(uint2*)(As + r * 260 + k) = *(uint2*)h4;
        }
        __syncthreads();
#pragma unroll
        for (int kt = 0; kt < 8; ++kt) {
            bf16x8 Af = *(const bf16x8*)(As + (wave * 16 + l15) * 260 + kt * 32 + quad * 8);
#pragma unroll
            for (int nt = 0; nt < 6; ++nt) {
                int col = nb * 96 + nt * 16 + l15;
                bf16x8 Bfr = *(const bf16x8*)(Wp + (size_t)col * KK + kh + kt * 32 + quad * 8);
                acc[nt] = __builtin_amdgcn_mfma_f32_16x16x32_bf16(Af, Bfr, acc[nt], 0, 0, 0);
            }
        }
    }
#pragma unroll
    for (int nt = 0; nt < 6; ++nt) {
        int col = nb * 96 + nt * 16 + l15;
        float bv = lds1(bp, col, f32);
#pragma unroll
        for (int r4 = 0; r4 < 4; ++r4) {
            int row = mb * 64 + wave * 16 + quad * 4 + r4;
            Cp[(size_t)row * G3 + col] = f2bf(acc[nt][r4] + bv);
        }
    }
}

// ---------------------------------------------------------------------------
// Scan machinery (round-4 proven config): 256 thr / 4 waves, 1 wave/EU.
// Each wave owns 192 cols: 96 B-frags = 64 AGPR-pinned + 32 VGPR-pinned.
#define LOAD_BFRAGS(Whc)                                                        \
    bf16x8 Ba[8][8]; bf16x8 Bv[8][4];                                           \
    _Pragma("unroll")                                                           \
    for (int nt = 0; nt < 12; ++nt) {                                           \
        int col = wave * 192 + nt * 16 + l15;                                   \
        _Pragma("unroll")                                                       \
        for (int kt = 0; kt < 8; ++kt) {                                        \
            bf16x8 f = *(const bf16x8*)(Whc + (size_t)col * 256 + kt * 32 + quad * 8); \
            if (nt < 8) Ba[kt][nt] = f; else Bv[kt][nt - 8] = f;                \
        }                                                                       \
    }                                                                           \
    _Pragma("unroll")                                                           \
    for (int kt = 0; kt < 8; ++kt) {                                            \
        _Pragma("unroll")                                                       \
        for (int nt = 0; nt < 8; ++nt) asm volatile("" : "+a"(Ba[kt][nt]));     \
        _Pragma("unroll")                                                       \
        for (int nt = 0; nt < 4; ++nt) asm volatile("" : "+v"(Bv[kt][nt]));     \
    }

#define MFMA_GH()                                                               \
    {                                                                           \
        f32x4 acc[12];                                                          \
        _Pragma("unroll")                                                       \
        for (int nt = 0; nt < 12; ++nt) acc[nt] = (f32x4){0.f, 0.f, 0.f, 0.f};  \
        _Pragma("unroll")                                                       \
        for (int kt = 0; kt < 8; ++kt) {                                        \
            bf16x8 Af = *(const bf16x8*)(hb + l15 * HBSTR + kt * 32 + quad * 8);\
            _Pragma("unroll")                                                   \
            for (int nt = 0; nt < 8; ++nt)                                      \
                acc[nt] = __builtin_amdgcn_mfma_f32_16x16x32_bf16(Af, Ba[kt][nt], acc[nt], 0, 0, 0); \
            _Pragma("unroll")                                                   \
            for (int nt = 0; nt < 4; ++nt)                                      \
                acc[8 + nt] = __builtin_amdgcn_mfma_f32_16x16x32_bf16(Af, Bv[kt][nt], acc[8 + nt], 0, 0, 0); \
        }                                                                       \
        if (quad < 2) {                                                         \
            _Pragma("unroll")                                                   \
            for (int nt = 0; nt < 12; ++nt) {                                   \
                int col = wave * 192 + nt * 16 + l15;                           \
                _Pragma("unroll")                                               \
                for (int r4 = 0; r4 < 4; ++r4) gh[quad * 4 + r4][col] = acc[nt][r4]; \
            }                                                                   \
        }                                                                       \
    }

// ---------------------------------------------------------------------------
// Token bidirectional GRU scan (blocks 0,1) + d_out zero-fill (blocks 2..255).
// Global stores issued AFTER the second barrier: the pre-barrier vmcnt(0)
// drain then only sees stores that are a full step old (latency hidden).
__global__ __attribute__((amdgpu_flat_work_group_size(256, 256), amdgpu_waves_per_eu(1, 1)))
void token_scan_zero(
    const unsigned short* __restrict__ gi_f, const unsigned short* __restrict__ gi_r,
    const unsigned short* __restrict__ Wh_fc, const unsigned short* __restrict__ Wh_rc,
    const void* __restrict__ bh_f, const void* __restrict__ bh_r,
    unsigned short* __restrict__ outp, void* __restrict__ dout,
    const void* __restrict__ emb) {

    const int f32 = detect_f32(emb);

    if (blockIdx.x >= 2) {
        uint4 z = {0u, 0u, 0u, 0u};
        uint4* p = (uint4*)dout;
        const size_t nvec = OUT_ELEMS * (f32 ? 4 : 2) / 16;
        size_t stride = (size_t)(gridDim.x - 2) * 256;
        for (size_t v = (size_t)(blockIdx.x - 2) * 256 + threadIdx.x; v < nvec; v += stride)
            p[v] = z;
        return;
    }

    const int dir = blockIdx.x;
    __shared__ float gh[BB][G3];
    __shared__ __align__(16) unsigned short hb[16 * HBSTR];
    __shared__ float bhs[G3];

    const int tid = threadIdx.x;
    const int wave = tid >> 6, lane = tid & 63;
    const int l15 = lane & 15, quad = lane >> 4;

    const unsigned short* Whc = dir ? Wh_rc : Wh_fc;
    const void* bh = dir ? bh_r : bh_f;
    const unsigned short* gi = dir ? gi_r : gi_f;

    LOAD_BFRAGS(Whc)

    for (int e = tid; e < 16 * HBSTR; e += 256) hb[e] = 0;    // h0 = 0, pads 0
    for (int c2 = tid; c2 < G3; c2 += 256) bhs[c2] = lds1(bh, c2, f32);
    float hreg[BB];
#pragma unroll
    for (int b = 0; b < BB; ++b) hreg[b] = 0.f;
    __syncthreads();

    const int c = tid;
    for (int t = 0; t < NN; ++t) {
        const int row = dir ? (NN - 1 - t) : t;
        // prefetch gi row (independent of MFMA phase -> latency hidden)
        unsigned short gpre[BB][3];
        const unsigned short* gp = gi + (size_t)row * BB * G3;
#pragma unroll
        for (int b = 0; b < BB; ++b) {
            gpre[b][0] = gp[b * G3 + c];
            gpre[b][1] = gp[b * G3 + c + 256];
            gpre[b][2] = gp[b * G3 + c + 512];
        }
        MFMA_GH()
        __syncthreads();
#pragma unroll
        for (int b = 0; b < BB; ++b) {
            float rr = sigm(bf2f(gpre[b][0]) + gh[b][c] + bhs[c]);
            float zz = sigm(bf2f(gpre[b][1]) + gh[b][c + 256] + bhs[c + 256]);
            float nn = tanh_fast(bf2f(gpre[b][2]) + rr * (gh[b][c + 512] + bhs[c + 512]));
            float hn = (1.f - zz) * nn + zz * hreg[b];
            hreg[b] = hn;
            hb[b * HBSTR + c] = f2bf(hn);
        }
        __syncthreads();
        // deferred global store (no pending vmem at the barrier above)
#pragma unroll
        for (int b = 0; b < BB; ++b)
            outp[((size_t)(row * BB + b)) * 512 + dir * 256 + c] = f2bf(hreg[b]);
    }
}

// ---------------------------------------------------------------------------
// Segment GRU scans: 256 blocks = (start i0, dir), 256 threads, 1 block/CU.
__global__ __attribute__((amdgpu_flat_work_group_size(256, 256), amdgpu_waves_per_eu(1, 1)))
void seg_scan(
    const unsigned short* __restrict__ gi,     // gi_s bf16 ws (1024 x 768)
    const unsigned short* __restrict__ Whc,    // Wh_s bf16 ws
    const void* __restrict__ bh,
    const void* __restrict__ h0f, const void* __restrict__ h0b,
    void* __restrict__ dout, const void* __restrict__ emb) {

    const int f32 = detect_f32(emb);

    __shared__ float gh[BB][G3];
    __shared__ __align__(16) unsigned short hb[16 * HBSTR];
    __shared__ float bhs[G3];

    const int tid = threadIdx.x;
    const int wave = tid >> 6, lane = tid & 63;
    const int l15 = lane & 15, quad = lane >> 4;
    const int dir = blockIdx.x & 1, i0 = blockIdx.x >> 1;

    LOAD_BFRAGS(Whc)

    const void* h0 = dir ? h0b : h0f;
    const size_t h0base = (size_t)i0 * (BB * SS);
    const int c = tid;
    float hreg[BB];
#pragma unroll
    for (int b = 0; b < BB; ++b) {
        float v = lds1(h0, h0base + b * 256 + c, f32);
        hreg[b] = v;
        hb[b * HBSTR + c] = f2bf(v);
    }
    for (int e = 8 * HBSTR + tid; e < 16 * HBSTR; e += 256) hb[e] = 0;
    for (int c2 = tid; c2 < G3; c2 += 256) bhs[c2] = lds1(bh, c2, f32);
    __syncthreads();

    const int nsteps = dir ? min(TT, i0 + 1) : min(TT, NN - i0);
    for (int t = 0; t < nsteps; ++t) {
        const int j = dir ? (i0 - t) : (i0 + t);
        unsigned short gpre[BB][3];
        const unsigned short* gp = gi + (size_t)j * BB * G3;
#pragma unroll
        for (int b = 0; b < BB; ++b) {
            gpre[b][0] = gp[b * G3 + c];
            gpre[b][1] = gp[b * G3 + c + 256];
            gpre[b][2] = gp[b * G3 + c + 512];
        }
        MFMA_GH()
        __syncthreads();

#pragma unroll
        for (int b = 0; b < BB; ++b) {
            float rr = sigm(bf2f(gpre[b][0]) + gh[b][c] + bhs[c]);
            float zz = sigm(bf2f(gpre[b][1]) + gh[b][c + 256] + bhs[c + 256]);
            float nn = tanh_fast(bf2f(gpre[b][2]) + rr * (gh[b][c + 512] + bhs[c + 512]));
            float hn = (1.f - zz) * nn + zz * hreg[b];
            hreg[b] = hn;
            hb[b * HBSTR + c] = f2bf(hn);
        }
        __syncthreads();

        // deferred global stores (issued after the barrier)
        const int r0 = dir ? j : i0;                 // triu pair (r0,c0), c0-r0=t
        const size_t tri = (size_t)r0 * NN - (size_t)(r0 * (r0 - 1)) / 2 + t;
        const size_t obase = tri * (BB * 512) + (dir ? 256 : 0);
#pragma unroll
        for (int b = 0; b < BB; ++b) {
            outw(dout, obase + b * 512 + c, hreg[b], f32);
            if (i0 == NN - 1) {
                if (dir == 0 && t == 0)      outw(dout, HIDOFF + b * 512 + c, hreg[b], f32);
                if (dir == 1 && t == TT - 1) outw(dout, HIDOFF + 256 + b * 512 + c, hreg[b], f32);
            }
        }
    }
}

// ---------------------------------------------------------------------------
extern "C" void kernel_launch(void* const* d_in, const int* in_sizes, int n_in,
                              void* d_out, int out_size, void* d_ws, size_t ws_size,
                              hipStream_t stream) {
    const int* tokens = (const int*)d_in[0];
    const void* emb   = d_in[1];
    const void* Wi_f  = d_in[2];
    const void* Wh_f  = d_in[3];
    const void* bi_f  = d_in[4];
    const void* bh_f  = d_in[5];
    const void* Wi_r  = d_in[6];
    const void* Wh_r  = d_in[7];
    const void* bi_r  = d_in[8];
    const void* bh_r  = d_in[9];
    const void* Wi_s  = d_in[10];
    const void* Wh_s  = d_in[11];
    const void* bi_s  = d_in[12];
    const void* bh_s  = d_in[13];
    const void* h0f   = d_in[14];
    const void* h0b   = d_in[15];

    unsigned short* wsu = (unsigned short*)d_ws;
    unsigned short* gif  = wsu;                 // 786432 halves (1.5 MB)
    unsigned short* gir  = wsu + 786432;        // 786432
    unsigned short* outp = wsu + 1572864;       // 524288 (1 MB)
    unsigned short* wcv  = wsu + 2097152;       // 1376256 (2.625 MB)
    unsigned short* gis  = gif;                 // alias (gif dead after token scan)
    // peak ws = 6.63 MB

    const unsigned short* Wi_fc = wcv;
    const unsigned short* Wi_rc = wcv + 196608;
    const unsigned short* Wh_fc = wcv + 393216;
    const unsigned short* Wh_rc = wcv + 589824;
    const unsigned short* Wh_sc = wcv + 786432;
    const unsigned short* Wi_sc = wcv + 983040;

    conv_all<<<dim3(672), dim3(256), 0, stream>>>(Wi_f, Wi_r, Wh_f, Wh_r, Wh_s, Wi_s,
                                                  wcv, emb);
    gemm_mfma<256><<<dim3(256), dim3(256), 0, stream>>>(
        tokens, emb, Wi_fc, bi_f, gif, Wi_rc, bi_r, gir, emb);
    token_scan_zero<<<dim3(256), dim3(256), 0, stream>>>(gif, gir, Wh_fc, Wh_rc,
                                                         bh_f, bh_r, outp, d_out, emb);
    gemm_mfma<512><<<dim3(128), dim3(256), 0, stream>>>(
        nullptr, outp, Wi_sc, bi_s, gis, nullptr, nullptr, nullptr, emb);
    seg_scan<<<dim3(256), dim3(256), 0, stream>>>(gis, Wh_sc, bh_s, h0f, h0b, d_out, emb);
}